// Round 3
// baseline (341.230 us; speedup 1.0000x reference)
//
#include <hip/hip_runtime.h>
#include <hip/hip_cooperative_groups.h>

namespace cg = cooperative_groups;

#define N_NODES 50000
#define N_EDGES 800000
#define NBKT 196          // dest buckets of 256 nodes
#define NBIN 392          // binning blocks (2048 edges each), 2 blocks/CU
#define BCAP 6144         // staging capacity per bucket
#define UTS 136           // LDS tile row stride (halves) in k_aggF

typedef __attribute__((ext_vector_type(4))) float floatx4;
typedef __attribute__((ext_vector_type(8))) _Float16 half8;
typedef __attribute__((ext_vector_type(4))) _Float16 half4;
typedef __attribute__((ext_vector_type(2))) _Float16 half2v;

// ---- workspace layout (bytes) ----
#define O_PTR   0UL          // int[N]
#define O_GF    200192UL     // int[NBKT] exact bucket totals (written, not atomic)
#define O_C     201216UL     // int[NBKT*NBIN] per-(bucket,block) counts
#define O_B     508672UL     // int[NBKT*NBIN] exclusive scan of C along blocks
#define O_DINV  816128UL     // float[N]
#define O_ESRC  1016320UL    // int[N_EDGES] 3.2MB
#define O_W1    4216320UL    // f16[128*128] (transposed [n][k])
#define O_W2    4249088UL    // f16[64*128]  (transposed [n][k])
#define O_STG   4265472UL    // u32 staging[NBKT*BCAP] = 4.8MB
#define O_H16   9082368UL    // f16[N*128] dinv-prescaled h
// end: 21882368 bytes (< proven 29.45MB footprint)

// One cooperative kernel replaces memset+binA+binB+conv (5 dispatches -> 2).
// Phases (grid.sync between):
//  P0  W transpose (grid-stride prologue, no deps)
//  P1a count: 2048 edges/block in regs, LDS histogram, write C[k][b]
//  P1b blocks<NBKT: exclusive scan C[b][*] -> B[b][*], total -> gfill[b]
//  P1c scatter staging from regs at B[bucket][block]+rank (atomic-free bases)
//  P2a blocks<NBKT: bucket CSR part 1 (hist+scan+ptr/dinv/cur)
//  P2b blocks<NBKT: esrc scatter  ||  blocks>=NBKT: vectorized h16 conv
__global__ __launch_bounds__(256) void k_pre(const int* __restrict__ ei,
                                             const float* __restrict__ h,
                                             const float* __restrict__ Wg,
                                             const float* __restrict__ Wf,
                                             int* __restrict__ gfill,
                                             int* __restrict__ C,
                                             int* __restrict__ B,
                                             int* __restrict__ ptr,
                                             float* __restrict__ dinv,
                                             int* __restrict__ esrc,
                                             _Float16* __restrict__ W1,
                                             _Float16* __restrict__ W2,
                                             unsigned* __restrict__ staging,
                                             _Float16* __restrict__ h16) {
    cg::grid_group grid = cg::this_grid();
    int b = blockIdx.x, t = threadIdx.x;

    // ---- P0: weight transpose (tiny, amortized over all blocks) ----
    for (int i = b * 256 + t; i < 16384; i += NBIN * 256) {
        int n = i >> 7, k = i & 127;
        W1[i] = (_Float16)Wg[k * 128 + n];
    }
    for (int i = b * 256 + t; i < 8192; i += NBIN * 256) {
        int n = i >> 7, k = i & 127;
        W2[i] = (_Float16)Wf[k * 64 + n];
    }

    // ---- P1a: count ----
    __shared__ int cnt[NBKT];
    __shared__ int s_i64;
    __shared__ int s_cb;
    if (t < 64) {                                  // wave 0: int64 probe
        unsigned w = ((const unsigned*)ei)[2 * t + 1];
        unsigned long long m = __ballot(w == 0u);
        if (t == 0) s_i64 = (__popcll(m) >= 60) ? 1 : 0;
    }
    for (int i = t; i < NBKT; i += 256) cnt[i] = 0;
    __syncthreads();
    bool i64 = s_i64 != 0;
    int e0 = b * 2048 + t * 8;                     // 8 edges per thread
    int sv[8], dvv[8];
    if (i64) {
        const int4* ps = (const int4*)(ei) + (e0 >> 1);
        const int4* pd = (const int4*)(ei + 2 * (size_t)N_EDGES) + (e0 >> 1);
#pragma unroll
        for (int g = 0; g < 4; ++g) {
            if (e0 + 2 * g < N_EDGES) {
                int4 s4 = ps[g], d4 = pd[g];
                sv[2 * g] = s4.x; sv[2 * g + 1] = s4.z;
                dvv[2 * g] = d4.x; dvv[2 * g + 1] = d4.z;
            } else { dvv[2 * g] = -1; dvv[2 * g + 1] = -1; }
        }
    } else {
        const int4* ps = (const int4*)(ei) + (e0 >> 2);
        const int4* pd = (const int4*)(ei + (size_t)N_EDGES) + (e0 >> 2);
#pragma unroll
        for (int g = 0; g < 2; ++g) {
            if (e0 + 4 * g < N_EDGES) {
                int4 s4 = ps[g], d4 = pd[g];
                sv[4 * g] = s4.x; sv[4 * g + 1] = s4.y; sv[4 * g + 2] = s4.z; sv[4 * g + 3] = s4.w;
                dvv[4 * g] = d4.x; dvv[4 * g + 1] = d4.y; dvv[4 * g + 2] = d4.z; dvv[4 * g + 3] = d4.w;
            } else { dvv[4 * g] = -1; dvv[4 * g + 1] = -1; dvv[4 * g + 2] = -1; dvv[4 * g + 3] = -1; }
        }
    }
    unsigned pk[8]; int rk[8]; short bk[8];
#pragma unroll
    for (int j = 0; j < 8; ++j) {
        int d = dvv[j];
        if (d >= 0 && e0 + j < N_EDGES) {
            int bkt = d >> 8;
            bk[j] = (short)bkt;
            pk[j] = (unsigned)sv[j] | ((unsigned)(d & 255) << 16);
            rk[j] = atomicAdd(&cnt[bkt], 1);       // local rank within (bucket, block)
        } else bk[j] = -1;
    }
    __syncthreads();
    for (int i = t; i < NBKT; i += 256)            // bucket-major: C[k][b]
        C[i * NBIN + b] = cnt[i];
    grid.sync();

    // ---- P1b: per-bucket exclusive scan over blocks ----
    __shared__ int sA[NBIN], sB[NBIN];
    if (b < NBKT) {
        for (int i = t; i < NBIN; i += 256) sA[i] = C[b * NBIN + i];
        __syncthreads();
        int* src = sA; int* dst = sB;
        for (int off = 1; off < NBIN; off <<= 1) { // Hillis-Steele, double-buffered
            for (int i = t; i < NBIN; i += 256)
                dst[i] = src[i] + ((i >= off) ? src[i - off] : 0);
            __syncthreads();
            int* tmp = src; src = dst; dst = tmp;
        }
        for (int i = t; i < NBIN; i += 256)        // exclusive = inclusive - own
            B[b * NBIN + i] = src[i] - C[b * NBIN + i];
        if (t == 0) gfill[b] = src[NBIN - 1];      // exact bucket total
    }
    grid.sync();

    // ---- P1c: scatter staging from registers ----
    __shared__ int gbase[NBKT];
    for (int i = t; i < NBKT; i += 256) gbase[i] = B[i * NBIN + b];
    __syncthreads();
#pragma unroll
    for (int j = 0; j < 8; ++j) {
        if (bk[j] >= 0) {
            int pos = gbase[bk[j]] + rk[j];
            if (pos < BCAP) staging[(size_t)bk[j] * BCAP + pos] = pk[j];
        }
    }
    grid.sync();

    // ---- P2a: bucket CSR (hist + scan + ptr/dinv/cur) ----
    __shared__ unsigned se[BCAP];
    __shared__ int lcnt[256];
    __shared__ int lscan[256];
    __shared__ int cur[256];
    int csr_cnt = 0;
    if (b < NBKT) {
        int nbase = b * 256;
        int nn = min(256, N_NODES - nbase);
        csr_cnt = min(gfill[b], BCAP);
        if (t < 64) {                              // CSR base: sum_{i<b} totals
            int acc = 0;
            for (int i = t; i < b; i += 64) acc += min(gfill[i], BCAP);
#pragma unroll
            for (int off = 32; off > 0; off >>= 1) acc += __shfl_down(acc, off);
            if (t == 0) s_cb = acc;
        }
        lcnt[t] = 0;
        __syncthreads();
        int cb = s_cb;
        const unsigned* st = staging + (size_t)b * BCAP;
        for (int i = t; i < csr_cnt; i += 256) {
            unsigned p = st[i];
            se[i] = p;
            atomicAdd(&lcnt[p >> 16], 1);
        }
        __syncthreads();
        int v = lcnt[t];
        lscan[t] = v;
        __syncthreads();
        for (int off = 1; off < 256; off <<= 1) {
            int x = (t >= off) ? lscan[t - off] : 0;
            __syncthreads(); lscan[t] += x; __syncthreads();
        }
        int segstart = cb + (lscan[t] - v);
        if (t < nn) {
            int node = nbase + t;
            ptr[node] = segstart;
            dinv[node] = rsqrtf((float)(v + 1));   // +1 = self-loop
            cur[t] = segstart;
        }
        __syncthreads();
    }
    grid.sync();

    // ---- P2b: esrc scatter || vectorized h16 conversion ----
    if (b < NBKT) {
        for (int i = t; i < csr_cnt; i += 256) {
            unsigned p = se[i];
            int pos = atomicAdd(&cur[p >> 16], 1);
            esrc[pos] = (int)(p & 0xffffu);
        }
    } else {
        __shared__ float sdv[256];
        int nb = (b - NBKT) * 256;
        int nn = min(256, N_NODES - nb);
        if (nn > 0) {
            if (t < nn) sdv[t] = dinv[nb + t];
            __syncthreads();
            const floatx4* src = (const floatx4*)(h + (size_t)nb * 128);
            half4* dst = (half4*)(h16 + (size_t)nb * 128);
            int nq = nn * 32;                      // 32 float4 per 128-wide row
            for (int i = t; i < nq; i += 256) {
                floatx4 v = src[i];
                float s = sdv[i >> 5];
                half4 o;
                o[0] = (_Float16)(v[0] * s); o[1] = (_Float16)(v[1] * s);
                o[2] = (_Float16)(v[2] * s); o[3] = (_Float16)(v[3] * s);
                dst[i] = o;
            }
        }
    }
}

// Fused aggregate + double GEMM. Block = 16 consecutive nodes (grid 3125).
// Round-8 proven form — UNCHANGED.
__global__ __launch_bounds__(256, 8) void k_aggF(const _Float16* __restrict__ h16,
                                                 const int* __restrict__ ptr,
                                                 const int* __restrict__ esrc,
                                                 const float* __restrict__ dinv,
                                                 const _Float16* __restrict__ W1,
                                                 const _Float16* __restrict__ W2,
                                                 const float* __restrict__ bg,
                                                 const float* __restrict__ bfc,
                                                 float* __restrict__ out) {
    __shared__ _Float16 ut[16 * UTS];
    __shared__ _Float16 z[16 * UTS];
    int wave = threadIdx.x >> 6;
    int lane = threadIdx.x & 63;
    int nb = blockIdx.x * 16;
    for (int q = 0; q < 4; ++q) {
        int node = nb + wave * 4 + q;
        int p0 = ptr[node];
        int p1 = (node + 1 < N_NODES) ? ptr[node + 1] : N_EDGES;
        half2v us = *(const half2v*)(h16 + (size_t)node * 128 + lane * 2);
        float a0 = (float)us[0], a1 = (float)us[1];           // self-loop
        for (int base = p0; base < p1; base += 64) {
            int cnt = p1 - base; if (cnt > 64) cnt = 64;
            int idx = 0;
            if (lane < cnt) idx = esrc[base + lane];
            int j = 0;
            for (; j + 8 <= cnt; j += 8) {
                int s0 = __shfl(idx, j),     s1 = __shfl(idx, j + 1);
                int s2 = __shfl(idx, j + 2), s3 = __shfl(idx, j + 3);
                int s4 = __shfl(idx, j + 4), s5 = __shfl(idx, j + 5);
                int s6 = __shfl(idx, j + 6), s7 = __shfl(idx, j + 7);
                half2v u0 = *(const half2v*)(h16 + (size_t)s0 * 128 + lane * 2);
                half2v u1 = *(const half2v*)(h16 + (size_t)s1 * 128 + lane * 2);
                half2v u2 = *(const half2v*)(h16 + (size_t)s2 * 128 + lane * 2);
                half2v u3 = *(const half2v*)(h16 + (size_t)s3 * 128 + lane * 2);
                half2v u4 = *(const half2v*)(h16 + (size_t)s4 * 128 + lane * 2);
                half2v u5 = *(const half2v*)(h16 + (size_t)s5 * 128 + lane * 2);
                half2v u6 = *(const half2v*)(h16 + (size_t)s6 * 128 + lane * 2);
                half2v u7 = *(const half2v*)(h16 + (size_t)s7 * 128 + lane * 2);
                a0 += (float)u0[0] + (float)u1[0] + (float)u2[0] + (float)u3[0]
                    + (float)u4[0] + (float)u5[0] + (float)u6[0] + (float)u7[0];
                a1 += (float)u0[1] + (float)u1[1] + (float)u2[1] + (float)u3[1]
                    + (float)u4[1] + (float)u5[1] + (float)u6[1] + (float)u7[1];
            }
            for (; j + 4 <= cnt; j += 4) {
                int s0 = __shfl(idx, j),     s1 = __shfl(idx, j + 1);
                int s2 = __shfl(idx, j + 2), s3 = __shfl(idx, j + 3);
                half2v u0 = *(const half2v*)(h16 + (size_t)s0 * 128 + lane * 2);
                half2v u1 = *(const half2v*)(h16 + (size_t)s1 * 128 + lane * 2);
                half2v u2 = *(const half2v*)(h16 + (size_t)s2 * 128 + lane * 2);
                half2v u3 = *(const half2v*)(h16 + (size_t)s3 * 128 + lane * 2);
                a0 += (float)u0[0] + (float)u1[0] + (float)u2[0] + (float)u3[0];
                a1 += (float)u0[1] + (float)u1[1] + (float)u2[1] + (float)u3[1];
            }
            for (; j < cnt; ++j) {
                int s = __shfl(idx, j);
                half2v uu = *(const half2v*)(h16 + (size_t)s * 128 + lane * 2);
                a0 += (float)uu[0]; a1 += (float)uu[1];
            }
        }
        float sc = dinv[node];
        int r = wave * 4 + q;
        ut[r * UTS + lane * 2]     = (_Float16)(a0 * sc);
        ut[r * UTS + lane * 2 + 1] = (_Float16)(a1 * sc);
    }
    __syncthreads();
    int quad = lane >> 4, l15 = lane & 15;
    half8 a[4];
#pragma unroll
    for (int kk = 0; kk < 4; ++kk)
        a[kk] = *(const half8*)(ut + l15 * UTS + kk * 32 + quad * 8);
#pragma unroll
    for (int tt = 0; tt < 2; ++tt) {               // GEMM1: wave does 2 of 8 n-tiles
        floatx4 acc = {0.f, 0.f, 0.f, 0.f};
        int n = (wave * 2 + tt) * 16 + l15;
#pragma unroll
        for (int kk = 0; kk < 4; ++kk) {
            half8 bb = *(const half8*)(W1 + n * 128 + kk * 32 + quad * 8);
            acc = __builtin_amdgcn_mfma_f32_16x16x32_f16(a[kk], bb, acc, 0, 0, 0);
        }
        float bias = bg[n];
#pragma unroll
        for (int i = 0; i < 4; ++i)
            z[(quad * 4 + i) * UTS + n] = (_Float16)fmaxf(acc[i] + bias, 0.f);
    }
    __syncthreads();
    half8 a2[4];
#pragma unroll
    for (int kk = 0; kk < 4; ++kk)
        a2[kk] = *(const half8*)(z + l15 * UTS + kk * 32 + quad * 8);
    {                                               // GEMM2: wave does 1 of 4 n-tiles
        floatx4 acc = {0.f, 0.f, 0.f, 0.f};
        int n = wave * 16 + l15;
#pragma unroll
        for (int kk = 0; kk < 4; ++kk) {
            half8 bb = *(const half8*)(W2 + n * 128 + kk * 32 + quad * 8);
            acc = __builtin_amdgcn_mfma_f32_16x16x32_f16(a2[kk], bb, acc, 0, 0, 0);
        }
        float bias = bfc[n];
#pragma unroll
        for (int i = 0; i < 4; ++i)
            out[(size_t)(nb + quad * 4 + i) * 64 + n] = acc[i] + bias;
    }
}

extern "C" void kernel_launch(void* const* d_in, const int* in_sizes, int n_in,
                              void* d_out, int out_size, void* d_ws, size_t ws_size,
                              hipStream_t stream) {
    (void)in_sizes; (void)n_in; (void)out_size; (void)ws_size;
    const float* h  = (const float*)d_in[0];
    const int*   ei = (const int*)d_in[1];
    const float* Wg = (const float*)d_in[2];
    const float* bg = (const float*)d_in[3];
    const float* Wf = (const float*)d_in[4];
    const float* bf = (const float*)d_in[5];
    float* out = (float*)d_out;

    char* ws = (char*)d_ws;
    int*      ptr   = (int*)(ws + O_PTR);
    int*      gfill = (int*)(ws + O_GF);
    int*      C     = (int*)(ws + O_C);
    int*      B     = (int*)(ws + O_B);
    float*    dinv  = (float*)(ws + O_DINV);
    int*      esrc  = (int*)(ws + O_ESRC);
    _Float16* W1    = (_Float16*)(ws + O_W1);
    _Float16* W2    = (_Float16*)(ws + O_W2);
    unsigned* staging = (unsigned*)(ws + O_STG);
    _Float16* h16   = (_Float16*)(ws + O_H16);

    void* args[] = { (void*)&ei, (void*)&h, (void*)&Wg, (void*)&Wf,
                     (void*)&gfill, (void*)&C, (void*)&B, (void*)&ptr,
                     (void*)&dinv, (void*)&esrc, (void*)&W1, (void*)&W2,
                     (void*)&staging, (void*)&h16 };
    hipLaunchCooperativeKernel((void*)k_pre, dim3(NBIN), dim3(256),
                               args, 0, stream);
    k_aggF<<<N_NODES / 16, 256, 0, stream>>>(h16, ptr, esrc, dinv,
                                             W1, W2, bg, bf, out);
}

// Round 5
// 154.076 us; speedup vs baseline: 2.2147x; 2.2147x over previous
//
#include <hip/hip_runtime.h>

#define N_NODES 50000
#define N_EDGES 800000
#define NBKT 782          // dest buckets of 64 nodes
#define BINB 196          // binning blocks (4096 edges each) — R0-proven form
#define BCAP 1792         // staging cap per bucket (mean 1024 + 24 sigma)
#define UTS 136           // LDS tile row stride (halves); breaks stride-128 conflicts

typedef __attribute__((ext_vector_type(4))) float floatx4;
typedef __attribute__((ext_vector_type(8))) _Float16 half8;
typedef __attribute__((ext_vector_type(4))) _Float16 half4;
typedef __attribute__((ext_vector_type(2))) _Float16 half2v;

// ---- workspace layout (bytes) ----
#define O_GF    0UL          // int[NBKT] bucket fill counts
#define O_W1    3200UL       // f16[128*128] (transposed [n][k])
#define O_W2    35968UL      // f16[64*128]  (transposed [n][k])
#define O_STG   52480UL      // u32 staging[NBKT*BCAP] = 5.6MB
#define O_H16   5657856UL    // f16[N*128] dinv-prescaled h
// end: 18457856 bytes (< proven 29.45MB footprint)

// Bin edges by dest>>6 into per-bucket staging runs. Identical to the R0-proven
// binA except bucket granularity (64 nodes).
// Blocks [BINB, BINB+96) transpose the weights to f16 (independent riders).
__global__ __launch_bounds__(256) void k_bin(const int* __restrict__ ei,
                                             int* __restrict__ gfill,
                                             unsigned* __restrict__ staging,
                                             const float* __restrict__ Wg,
                                             const float* __restrict__ Wf,
                                             _Float16* __restrict__ W1,
                                             _Float16* __restrict__ W2) {
    int b = blockIdx.x, t = threadIdx.x;
    if (b >= BINB) {                               // weight-transpose rider blocks
        int wb = b - BINB;
        if (wb < 64) {
            int i = wb * 256 + t;                  // W1: 16384 elems
            int n = i >> 7, k = i & 127;
            W1[i] = (_Float16)Wg[k * 128 + n];
        } else {
            int i = (wb - 64) * 256 + t;           // W2: 8192 elems
            int n = i >> 7, k = i & 127;
            W2[i] = (_Float16)Wf[k * 64 + n];
        }
        return;
    }
    __shared__ int cnt[NBKT];
    __shared__ int gbase[NBKT];
    __shared__ int s_i64;
    if (t < 64) {                                  // wave 0: int64 probe
        unsigned w = ((const unsigned*)ei)[2 * t + 1];
        unsigned long long m = __ballot(w == 0u);
        if (t == 0) s_i64 = (__popcll(m) >= 60) ? 1 : 0;
    }
    for (int i = t; i < NBKT; i += 256) cnt[i] = 0;
    __syncthreads();
    bool i64 = s_i64 != 0;
    int e0 = b * 4096 + t * 16;                    // 16 edges per thread (R0 form)
    int sv[16], dvv[16];
    if (i64) {
        const int4* ps = (const int4*)(ei) + (e0 >> 1);
        const int4* pd = (const int4*)(ei + 2 * (size_t)N_EDGES) + (e0 >> 1);
#pragma unroll
        for (int g = 0; g < 8; ++g) {
            if (e0 + 2 * g < N_EDGES) {
                int4 s4 = ps[g], d4 = pd[g];
                sv[2 * g] = s4.x; sv[2 * g + 1] = s4.z;
                dvv[2 * g] = d4.x; dvv[2 * g + 1] = d4.z;
            } else { dvv[2 * g] = -1; dvv[2 * g + 1] = -1; }
        }
    } else {
        const int4* ps = (const int4*)(ei) + (e0 >> 2);
        const int4* pd = (const int4*)(ei + (size_t)N_EDGES) + (e0 >> 2);
#pragma unroll
        for (int g = 0; g < 4; ++g) {
            if (e0 + 4 * g < N_EDGES) {
                int4 s4 = ps[g], d4 = pd[g];
                sv[4 * g] = s4.x; sv[4 * g + 1] = s4.y; sv[4 * g + 2] = s4.z; sv[4 * g + 3] = s4.w;
                dvv[4 * g] = d4.x; dvv[4 * g + 1] = d4.y; dvv[4 * g + 2] = d4.z; dvv[4 * g + 3] = d4.w;
            } else { dvv[4 * g] = -1; dvv[4 * g + 1] = -1; dvv[4 * g + 2] = -1; dvv[4 * g + 3] = -1; }
        }
    }
    unsigned pk[16]; int rk[16]; short bk[16];
#pragma unroll
    for (int j = 0; j < 16; ++j) {
        int d = dvv[j];
        if (d >= 0 && e0 + j < N_EDGES) {
            int bkt = d >> 6;                      // 64-node bucket
            bk[j] = (short)bkt;
            pk[j] = (unsigned)sv[j] | ((unsigned)(d & 63) << 16);
            rk[j] = atomicAdd(&cnt[bkt], 1);
        } else bk[j] = -1;
    }
    __syncthreads();
    for (int i = t; i < NBKT; i += 256)
        gbase[i] = atomicAdd(&gfill[i], cnt[i]);
    __syncthreads();
#pragma unroll
    for (int j = 0; j < 16; ++j) {
        if (bk[j] >= 0) {
            int pos = gbase[bk[j]] + rk[j];
            if (pos < BCAP) staging[(size_t)bk[j] * BCAP + pos] = pk[j];
        }
    }
}

// h16 = f16(h * dinv[row]). dinv computed LOCALLY from the 2 bucket runs
// covering this block's 128 rows (deg histogram of staged tags).
__global__ __launch_bounds__(256) void k_conv(const float* __restrict__ h,
                                              const int* __restrict__ gfill,
                                              const unsigned* __restrict__ staging,
                                              _Float16* __restrict__ h16) {
    __shared__ int deg[128];
    __shared__ float sdv[128];
    int b = blockIdx.x, t = threadIdx.x;
    int nb = b * 128;
    int nn = min(128, N_NODES - nb);
    if (nn <= 0) return;
    if (t < 128) deg[t] = 0;
    __syncthreads();
#pragma unroll
    for (int kb = 0; kb < 2; ++kb) {
        int gb = b * 2 + kb;                       // grid 391 -> gb <= 781 < NBKT
        int cnt = min(gfill[gb], BCAP);
        const unsigned* st = staging + (size_t)gb * BCAP;
        for (int i = t; i < cnt; i += 256)
            atomicAdd(&deg[kb * 64 + (st[i] >> 16)], 1);
    }
    __syncthreads();
    if (t < 128) sdv[t] = rsqrtf((float)(deg[t] + 1));   // +1 = self-loop
    __syncthreads();
    const floatx4* src = (const floatx4*)(h + (size_t)nb * 128);
    half4* dst = (half4*)(h16 + (size_t)nb * 128);
    int nq = nn * 32;                              // 32 float4 per 128-wide row
    for (int i = t; i < nq; i += 256) {
        floatx4 v = src[i];
        float s = sdv[i >> 5];
        half4 o;
        o[0] = (_Float16)(v[0] * s); o[1] = (_Float16)(v[1] * s);
        o[2] = (_Float16)(v[2] * s); o[3] = (_Float16)(v[3] * s);
        dst[i] = o;
    }
}

// Fused aggregate + double GEMM. Block = 16 consecutive nodes (grid 3125).
// Prologue builds per-node edge lists in LDS from the bucket staging
// (replaces binB's ptr/esrc/dinv). MLP/GEMM body is the round-8 proven form,
// with esrc->LDS se[], ptr->seg16[], dinv->sdv16[].
__global__ __launch_bounds__(256, 8) void k_aggF(const _Float16* __restrict__ h16,
                                                 const int* __restrict__ gfill,
                                                 const unsigned* __restrict__ staging,
                                                 const _Float16* __restrict__ W1,
                                                 const _Float16* __restrict__ W2,
                                                 const float* __restrict__ bg,
                                                 const float* __restrict__ bfc,
                                                 float* __restrict__ out) {
    __shared__ _Float16 ut[16 * UTS];
    __shared__ _Float16 z[16 * UTS];
    __shared__ unsigned short se[BCAP];            // 3.5KB per-node lists
    __shared__ int deg16[16], seg16[16], cur16[16];
    __shared__ float sdv16[16];
    int t = threadIdx.x;
    int wave = t >> 6;
    int lane = t & 63;
    int nb = blockIdx.x * 16;
    int bkt = blockIdx.x >> 2;                     // 64-node bucket
    unsigned lo = (unsigned)(blockIdx.x & 3) * 16; // our 16-tag window
    int cnt = min(gfill[bkt], BCAP);
    if (t < 16) deg16[t] = 0;
    __syncthreads();
    const unsigned* st = staging + (size_t)bkt * BCAP;
    unsigned held[7];                              // static-indexed (no scratch)
#pragma unroll
    for (int r = 0; r < 7; ++r) {
        int i = t + r * 256;
        unsigned p = 0xFFFFFFFFu;
        if (i < cnt) p = st[i];
        unsigned tg = p >> 16;
        if (tg - lo < 16u) atomicAdd(&deg16[tg - lo], 1);
        else p = 0xFFFFFFFFu;
        held[r] = p;
    }
    __syncthreads();
    if (t == 0) {
        int s = 0;
#pragma unroll
        for (int k = 0; k < 16; ++k) { seg16[k] = s; cur16[k] = s; s += deg16[k]; }
    }
    if (t < 16) sdv16[t] = rsqrtf((float)(deg16[t] + 1));  // matches k_conv bit-exact
    __syncthreads();
#pragma unroll
    for (int r = 0; r < 7; ++r) {
        unsigned p = held[r];
        if (p != 0xFFFFFFFFu) {
            int rk = atomicAdd(&cur16[(p >> 16) - lo], 1);
            if (rk < BCAP) se[rk] = (unsigned short)(p & 0xffffu);
        }
    }
    __syncthreads();
    for (int q = 0; q < 4; ++q) {
        int tag = wave * 4 + q;
        int node = nb + tag;
        int p0 = seg16[tag];
        int p1 = p0 + deg16[tag];
        half2v us = *(const half2v*)(h16 + (size_t)node * 128 + lane * 2);
        float a0 = (float)us[0], a1 = (float)us[1];           // self-loop
        for (int base = p0; base < p1; base += 64) {
            int c = p1 - base; if (c > 64) c = 64;
            int idx = 0;
            if (lane < c) idx = se[base + lane];
            int j = 0;
            for (; j + 8 <= c; j += 8) {
                int s0 = __shfl(idx, j),     s1 = __shfl(idx, j + 1);
                int s2 = __shfl(idx, j + 2), s3 = __shfl(idx, j + 3);
                int s4 = __shfl(idx, j + 4), s5 = __shfl(idx, j + 5);
                int s6 = __shfl(idx, j + 6), s7 = __shfl(idx, j + 7);
                half2v u0 = *(const half2v*)(h16 + (size_t)s0 * 128 + lane * 2);
                half2v u1 = *(const half2v*)(h16 + (size_t)s1 * 128 + lane * 2);
                half2v u2 = *(const half2v*)(h16 + (size_t)s2 * 128 + lane * 2);
                half2v u3 = *(const half2v*)(h16 + (size_t)s3 * 128 + lane * 2);
                half2v u4 = *(const half2v*)(h16 + (size_t)s4 * 128 + lane * 2);
                half2v u5 = *(const half2v*)(h16 + (size_t)s5 * 128 + lane * 2);
                half2v u6 = *(const half2v*)(h16 + (size_t)s6 * 128 + lane * 2);
                half2v u7 = *(const half2v*)(h16 + (size_t)s7 * 128 + lane * 2);
                a0 += (float)u0[0] + (float)u1[0] + (float)u2[0] + (float)u3[0]
                    + (float)u4[0] + (float)u5[0] + (float)u6[0] + (float)u7[0];
                a1 += (float)u0[1] + (float)u1[1] + (float)u2[1] + (float)u3[1]
                    + (float)u4[1] + (float)u5[1] + (float)u6[1] + (float)u7[1];
            }
            for (; j + 4 <= c; j += 4) {
                int s0 = __shfl(idx, j),     s1 = __shfl(idx, j + 1);
                int s2 = __shfl(idx, j + 2), s3 = __shfl(idx, j + 3);
                half2v u0 = *(const half2v*)(h16 + (size_t)s0 * 128 + lane * 2);
                half2v u1 = *(const half2v*)(h16 + (size_t)s1 * 128 + lane * 2);
                half2v u2 = *(const half2v*)(h16 + (size_t)s2 * 128 + lane * 2);
                half2v u3 = *(const half2v*)(h16 + (size_t)s3 * 128 + lane * 2);
                a0 += (float)u0[0] + (float)u1[0] + (float)u2[0] + (float)u3[0];
                a1 += (float)u0[1] + (float)u1[1] + (float)u2[1] + (float)u3[1];
            }
            for (; j < c; ++j) {
                int s = __shfl(idx, j);
                half2v uu = *(const half2v*)(h16 + (size_t)s * 128 + lane * 2);
                a0 += (float)uu[0]; a1 += (float)uu[1];
            }
        }
        float sc = sdv16[tag];
        int r = wave * 4 + q;
        ut[r * UTS + lane * 2]     = (_Float16)(a0 * sc);
        ut[r * UTS + lane * 2 + 1] = (_Float16)(a1 * sc);
    }
    __syncthreads();
    int quad = lane >> 4, l15 = lane & 15;
    half8 a[4];
#pragma unroll
    for (int kk = 0; kk < 4; ++kk)
        a[kk] = *(const half8*)(ut + l15 * UTS + kk * 32 + quad * 8);
#pragma unroll
    for (int tt = 0; tt < 2; ++tt) {               // GEMM1: wave does 2 of 8 n-tiles
        floatx4 acc = {0.f, 0.f, 0.f, 0.f};
        int n = (wave * 2 + tt) * 16 + l15;
#pragma unroll
        for (int kk = 0; kk < 4; ++kk) {
            half8 bb = *(const half8*)(W1 + n * 128 + kk * 32 + quad * 8);
            acc = __builtin_amdgcn_mfma_f32_16x16x32_f16(a[kk], bb, acc, 0, 0, 0);
        }
        float bias = bg[n];
#pragma unroll
        for (int i = 0; i < 4; ++i)
            z[(quad * 4 + i) * UTS + n] = (_Float16)fmaxf(acc[i] + bias, 0.f);
    }
    __syncthreads();
    half8 a2[4];
#pragma unroll
    for (int kk = 0; kk < 4; ++kk)
        a2[kk] = *(const half8*)(z + l15 * UTS + kk * 32 + quad * 8);
    {                                               // GEMM2: wave does 1 of 4 n-tiles
        floatx4 acc = {0.f, 0.f, 0.f, 0.f};
        int n = wave * 16 + l15;
#pragma unroll
        for (int kk = 0; kk < 4; ++kk) {
            half8 bb = *(const half8*)(W2 + n * 128 + kk * 32 + quad * 8);
            acc = __builtin_amdgcn_mfma_f32_16x16x32_f16(a2[kk], bb, acc, 0, 0, 0);
        }
        float bias = bfc[n];
#pragma unroll
        for (int i = 0; i < 4; ++i)
            out[(size_t)(nb + quad * 4 + i) * 64 + n] = acc[i] + bias;
    }
}

extern "C" void kernel_launch(void* const* d_in, const int* in_sizes, int n_in,
                              void* d_out, int out_size, void* d_ws, size_t ws_size,
                              hipStream_t stream) {
    (void)in_sizes; (void)n_in; (void)out_size; (void)ws_size;
    const float* h  = (const float*)d_in[0];
    const int*   ei = (const int*)d_in[1];
    const float* Wg = (const float*)d_in[2];
    const float* bg = (const float*)d_in[3];
    const float* Wf = (const float*)d_in[4];
    const float* bf = (const float*)d_in[5];
    float* out = (float*)d_out;

    char* ws = (char*)d_ws;
    int*      gfill = (int*)(ws + O_GF);
    _Float16* W1    = (_Float16*)(ws + O_W1);
    _Float16* W2    = (_Float16*)(ws + O_W2);
    unsigned* staging = (unsigned*)(ws + O_STG);
    _Float16* h16   = (_Float16*)(ws + O_H16);

    hipMemsetAsync(gfill, 0, NBKT * sizeof(int), stream);
    k_bin<<<BINB + 96, 256, 0, stream>>>(ei, gfill, staging, Wg, Wf, W1, W2);
    k_conv<<<(N_NODES + 127) / 128, 256, 0, stream>>>(h, gfill, staging, h16);
    k_aggF<<<N_NODES / 16, 256, 0, stream>>>(h16, gfill, staging,
                                             W1, W2, bg, bf, out);
}